// Round 10
// baseline (2049.112 us; speedup 1.0000x reference)
//
#include <hip/hip_runtime.h>

// Problem shape (fixed by setup_inputs): B=4, N=16384, NPOINT=1024, nsample=1,
// radius=0.5. xyz input layout is [B,3,N]. Output: int32 [B,NPOINT,1].
//
// Round-10 structure: FPS split across 8 blocks per batch (32 blocks total,
// trivially co-resident on 256 CUs -> no dispatch-order deadlock risk).
// Rationale: rounds 0-9 established a ~3080 VALU-busy-cycle/iter floor for
// the single-block scan (invariant across 4 reduce implementations) -> the
// binding constraint is 4 busy CUs out of 256. Each block owns 2048 points
// (KPT=4 in registers), computes its local tagged max via the HW-verified
// DPP reduce, and blocks synchronize per iteration through device-scope
// atomics using the R9-verified monotone-tag protocol lifted to global:
//   key = [tag:11 | value-bits:32 | (16383-idx):14], tag = seq (monotone)
//   -> stale slot contents lose automatically, no reset, no reset race.
//   Two rotating slots make read(seq)/write(seq+1) epochs disjoint (same
//   2-slot argument as R9: a block can only reach seq s after all blocks
//   posted s-1, which happens only after they read slot of s-2).
//   Arrival counter: fetch_add(RELEASE) after the max; spin on
//   load(ACQUIRE) until NBLK*seq, then read the slot (ordered by acquire).
// Spin carries a 2^16-poll bailout: a protocol bug degrades to a wrong
// answer, never a hung container.
// Distance math replicated exactly as numpy: ((dx*dx+dy*dy)+dz*dz), each op
// RN, no FMA contraction. Tie-break: within equal tag+value, larger
// (16383-idx) wins == smaller index == numpy argmax first-occurrence.

constexpr int N_PTS       = 16384;
constexpr int NPOINT      = 1024;
constexpr int BLOCK       = 512;                  // 8 waves
constexpr int NBLK        = 8;                    // blocks per batch
constexpr int PTS_PER_BLK = N_PTS / NBLK;         // 2048
constexpr int KPT         = PTS_PER_BLK / BLOCK;  // 4 points/thread
constexpr int NWAVE       = BLOCK / 64;           // 8
constexpr int SYNC_U32    = 32;                   // 128 B per batch (no false
                                                  // sharing between batches)

// key = [tag:11 @46 | float-bits:32 @14 | (16383-idx):14 @0]
__device__ inline unsigned long long pack_key(unsigned tag, float v, int idx) {
    return ((unsigned long long)tag << 46) |
           ((unsigned long long)__float_as_uint(v) << 14) |
           (unsigned)(N_PTS - 1 - idx);
}
__device__ inline unsigned long long umax64(unsigned long long a,
                                            unsigned long long b) {
    return a > b ? a : b;
}

// One DPP max step on a u64 key (HW-verified rounds 5-9): move both 32-bit
// halves with the same control, u64-max with the unmoved key. bound_ctrl=false
// + old=self makes masked lanes a max-identity.
template <int CTRL, int RM, int BM>
__device__ inline unsigned long long dpp_max_step(unsigned long long key) {
    const int lo = (int)(unsigned)key;
    const int hi = (int)(unsigned)(key >> 32);
    const unsigned mlo =
        (unsigned)__builtin_amdgcn_update_dpp(lo, lo, CTRL, RM, BM, false);
    const unsigned mhi =
        (unsigned)__builtin_amdgcn_update_dpp(hi, hi, CTRL, RM, BM, false);
    const unsigned long long moved = ((unsigned long long)mhi << 32) | mlo;
    return key > moved ? key : moved;
}
// Full 64-lane max; result valid in lane 63 (HW-verified rounds 5-7).
__device__ inline unsigned long long wave_max_key(unsigned long long key) {
    key = dpp_max_step<0x111, 0xf, 0xf>(key);  // row_shr:1
    key = dpp_max_step<0x112, 0xf, 0xf>(key);  // row_shr:2
    key = dpp_max_step<0x114, 0xf, 0xe>(key);  // row_shr:4
    key = dpp_max_step<0x118, 0xf, 0xc>(key);  // row_shr:8
    key = dpp_max_step<0x142, 0xa, 0xf>(key);  // row_bcast:15
    key = dpp_max_step<0x143, 0xc, 0xf>(key);  // row_bcast:31
    return key;
}

// Leader-lane cross-block exchange for sequence number 'seq' (>=1, monotone).
// Returns the decoded global argmax index (inherently in [0, N_PTS)).
__device__ inline int sync_exchange(unsigned long long* slots, unsigned* cnt,
                                    unsigned long long key, unsigned seq) {
    const int si = (int)((seq + 1) & 1);
    atomicMax(&slots[si], key);                       // device scope
    __hip_atomic_fetch_add(cnt, 1u, __ATOMIC_RELEASE,
                           __HIP_MEMORY_SCOPE_AGENT); // orders the max
    const unsigned target = (unsigned)NBLK * seq;
    unsigned guard = 0;
    while (__hip_atomic_load(cnt, __ATOMIC_ACQUIRE,
                             __HIP_MEMORY_SCOPE_AGENT) < target) {
        if (++guard > (1u << 16)) break;              // fail-safe: no hang
    }
    const unsigned long long fin = __hip_atomic_load(
        &slots[si], __ATOMIC_RELAXED, __HIP_MEMORY_SCOPE_AGENT);
    return N_PTS - 1 - (int)(fin & 0x3FFFu);
}

__global__ void init_sync(unsigned* __restrict__ sync, int n) {
    const int i = blockIdx.x * blockDim.x + threadIdx.x;
    if (i < n) sync[i] = 0u;
}

__global__ __launch_bounds__(BLOCK) void fps_kernel(
    const float* __restrict__ xyz,    // [B,3,N]
    int* __restrict__ cent,           // [B,NPOINT] workspace
    unsigned* __restrict__ sync)      // [B][SYNC_U32] sync records
{
    const int b   = blockIdx.x / NBLK;
    const int blk = blockIdx.x % NBLK;
    const int tid = threadIdx.x;
    const float* X = xyz + (size_t)b * 3 * N_PTS;
    const float* Y = X + N_PTS;
    const float* Z = X + 2 * N_PTS;

    unsigned long long* slots =
        (unsigned long long*)(sync + (size_t)b * SYNC_U32);
    unsigned* cnt = sync + (size_t)b * SYNC_U32 + 4;   // after 2x u64

    const int base = blk * PTS_PER_BLK;
    float px[KPT], py[KPT], pz[KPT], dst[KPT];
#pragma unroll
    for (int k = 0; k < KPT; ++k) {
        const int p = base + tid + k * BLOCK;   // coalesced, ascending/thread
        px[k] = X[p];
        py[k] = Y[p];
        pz[k] = Z[p];
        dst[k] = 1e10f;                          // BIG
    }

    __shared__ unsigned long long s_key[NWAVE];
    __shared__ int s_far;

    const int wave = tid >> 6;
    const int lane = tid & 63;

    // ---- initial far: argmax over x (first occurrence), seq = 1 ----
    int far;
    {
        float bv = px[0];
        int   bk = 0;
#pragma unroll
        for (int k = 1; k < KPT; ++k) {
            if (px[k] > bv) { bv = px[k]; bk = k; }
        }
        const unsigned long long key =
            wave_max_key(pack_key(1u, bv, base + tid + bk * BLOCK));
        if (lane == 63) s_key[wave] = key;
        __syncthreads();
        if (tid == 0) {
            const unsigned long long bkk =
                umax64(umax64(umax64(s_key[0], s_key[1]),
                              umax64(s_key[2], s_key[3])),
                       umax64(umax64(s_key[4], s_key[5]),
                              umax64(s_key[6], s_key[7])));
            s_far = sync_exchange(slots, cnt, bkk, 1u);
        }
        __syncthreads();
        far = __builtin_amdgcn_readfirstlane(s_far) & (N_PTS - 1);
    }

    // ---- main FPS loop ----
    for (int it = 0; it < NPOINT; ++it) {
        if (blk == 0 && tid == 0) cent[b * NPOINT + it] = far;  // PRE-update
        if (it == NPOINT - 1) break;                            // last unused

        // centroid coords: far is uniform (SGPR) -> scalar broadcast loads
        const float cx = X[far];
        const float cy = Y[far];
        const float cz = Z[far];

        float nbv = -1.0f;
        int   nbk = 0;
#pragma unroll
        for (int k = 0; k < KPT; ++k) {
            const float dx = __fsub_rn(px[k], cx);
            const float dy = __fsub_rn(py[k], cy);
            const float dz = __fsub_rn(pz[k], cz);
            const float d  = __fadd_rn(
                __fadd_rn(__fmul_rn(dx, dx), __fmul_rn(dy, dy)),
                __fmul_rn(dz, dz));
            const float nd = fminf(dst[k], d);
            dst[k] = nd;
            if (nd > nbv) { nbv = nd; nbk = k; }
        }

        const unsigned long long key = wave_max_key(
            pack_key((unsigned)(it + 2), nbv, base + tid + nbk * BLOCK));
        if (lane == 63) s_key[wave] = key;
        __syncthreads();                         // barrier 1: keys published
        if (tid == 0) {
            const unsigned long long bkk =
                umax64(umax64(umax64(s_key[0], s_key[1]),
                              umax64(s_key[2], s_key[3])),
                       umax64(umax64(s_key[4], s_key[5]),
                              umax64(s_key[6], s_key[7])));
            s_far = sync_exchange(slots, cnt, bkk, (unsigned)(it + 2));
        }
        __syncthreads();                         // barrier 2: far published
        far = __builtin_amdgcn_readfirstlane(s_far) & (N_PTS - 1);
    }
}

// ---------------------------------------------------------------------------
// Ball query, nsample=1: one wave per centroid; scan 64-point chunks from
// index 0, first hit wins (== min index within radius). Distance replicated
// as the reference einsum: ((-2*dot) + |c|^2) + |p|^2; keep-test d <= 0.25.
// ---------------------------------------------------------------------------
__global__ __launch_bounds__(256) void ballq_kernel(
    const float* __restrict__ xyz,   // [B,3,N]
    const int* __restrict__ cent,    // [B,NPOINT]
    int* __restrict__ out)           // [B,NPOINT]
{
    const int gw   = (blockIdx.x * 256 + threadIdx.x) >> 6; // global wave id
    const int lane = threadIdx.x & 63;
    const int b = gw / NPOINT;
    const int s = gw % NPOINT;

    const float* X = xyz + (size_t)b * 3 * N_PTS;
    const float* Y = X + N_PTS;
    const float* Z = X + 2 * N_PTS;

    const int ci = cent[b * NPOINT + s] & (N_PTS - 1);  // fault guard
    const float cx = X[ci];
    const float cy = Y[ci];
    const float cz = Z[ci];
    const float cn = __fadd_rn(
        __fadd_rn(__fmul_rn(cx, cx), __fmul_rn(cy, cy)), __fmul_rn(cz, cz));

    int res = N_PTS;
    for (int base = 0; base < N_PTS; base += 64) {
        const int p = base + lane;
        const float x = X[p];
        const float y = Y[p];
        const float z = Z[p];
        const float dot = __fadd_rn(
            __fadd_rn(__fmul_rn(x, cx), __fmul_rn(y, cy)), __fmul_rn(z, cz));
        const float pn = __fadd_rn(
            __fadd_rn(__fmul_rn(x, x), __fmul_rn(y, y)), __fmul_rn(z, z));
        const float d = __fadd_rn(__fadd_rn(__fmul_rn(-2.0f, dot), cn), pn);
        const bool hit = !(d > 0.25f);
        const unsigned long long m = __ballot(hit);
        if (m) {                       // wave-uniform branch
            res = base + (__ffsll((long long)m) - 1);
            break;
        }
    }
    if (lane == 0) out[b * NPOINT + s] = res;
}

extern "C" void kernel_launch(void* const* d_in, const int* in_sizes, int n_in,
                              void* d_out, int out_size, void* d_ws, size_t ws_size,
                              hipStream_t stream) {
    const float* xyz = (const float*)d_in[0];
    const int B = in_sizes[1] / 16;          // cls_label is [B,16]
    int* cent = (int*)d_ws;                  // [B, NPOINT] scratch
    unsigned* sync = (unsigned*)d_ws + (size_t)B * NPOINT;  // [B][SYNC_U32]
    int* out  = (int*)d_out;                 // int32 [B, NPOINT, 1]

    init_sync<<<1, 256, 0, stream>>>(sync, B * SYNC_U32);
    fps_kernel<<<B * NBLK, BLOCK, 0, stream>>>(xyz, cent, sync);

    const int nwaves  = B * NPOINT;          // one wave per centroid
    const int nblocks = nwaves / 4;          // 256 threads = 4 waves/block
    ballq_kernel<<<nblocks, 256, 0, stream>>>(xyz, cent, out);
}

// Round 11
// 1877.123 us; speedup vs baseline: 1.0916x; 1.0916x over previous
//
#include <hip/hip_runtime.h>

// Problem shape (fixed by setup_inputs): B=4, N=16384, NPOINT=1024, nsample=1,
// radius=0.5. xyz input layout is [B,3,N]. Output: int32 [B,NPOINT,1].
//
// FPS: one block per batch (R10 measured cross-block device-scope sync at
// ~1.9 us/iter — more than a whole single-block iteration; multi-block is
// dead). 512 threads = 8 waves = 2 waves/SIMD, 32 points/thread.
//
// Round-11 change vs R6 (single variable): the entire 32-point distance +
// argmax scan is ONE inline-asm block with every coordinate and dst bound as
// an arch-VGPR ("v") operand. Rationale: across R0/R3/R6/R9 measured VALU
// cycles/iter ~ 3080 vs ~1900 static — and VGPR_Count ~ 92 vs ~150 live
// values in every variant: the allocator parks the point cloud in the
// unified AGPR file and pays v_accvgpr_read (a VALU op) per access per
// iteration. "v" constraints are unsatisfiable from AGPRs, so this forces
// true arch-VGPR residency (budget 256 at waves_per_eu(2,2)) and pins the
// scan at exactly 384 issue slots.
// Asm semantics == the verified C++ exactly: per point
//   t=p-c (v_sub RN) ; t*t (v_mul RN) ; sums (v_add RN, ((x+y)+z) order) ;
//   dst=min(dst,d) (v_min) ; cmp d<=bv keeps old (strict '>' update with
//   ascending k == numpy first-occurrence) ; cndmask bv/bi, k inline const.
// Reduce/tail unchanged from R6 (HW-verified): pack (val<<32|16383-idx) ->
// 6-step DPP wave max -> lane63 LDS write (double-buffered) -> ONE barrier ->
// 8-key tree -> readfirstlane -> masked far.

constexpr int N_PTS  = 16384;
constexpr int NPOINT = 1024;
constexpr int BLOCK  = 512;            // 8 waves -> 2 waves/SIMD
constexpr int KPT    = N_PTS / BLOCK;  // 32 points/thread
constexpr int NWAVE  = BLOCK / 64;     // 8

__device__ inline unsigned long long pack_key(float v, int idx) {
    return ((unsigned long long)__float_as_uint(v) << 32) |
           (unsigned)(N_PTS - 1 - idx);
}
__device__ inline int key_idx(unsigned long long k) {
    return N_PTS - 1 - (int)(k & 0xFFFFu);
}
__device__ inline unsigned long long umax64(unsigned long long a,
                                            unsigned long long b) {
    return a > b ? a : b;
}

template <int CTRL, int RM, int BM>
__device__ inline unsigned long long dpp_max_step(unsigned long long key) {
    const int lo = (int)(unsigned)key;
    const int hi = (int)(unsigned)(key >> 32);
    const unsigned mlo =
        (unsigned)__builtin_amdgcn_update_dpp(lo, lo, CTRL, RM, BM, false);
    const unsigned mhi =
        (unsigned)__builtin_amdgcn_update_dpp(hi, hi, CTRL, RM, BM, false);
    const unsigned long long moved = ((unsigned long long)mhi << 32) | mlo;
    return key > moved ? key : moved;
}
// Full 64-lane max; result valid in lane 63 (HW-verified rounds 5-9).
__device__ inline unsigned long long wave_max_key(unsigned long long key) {
    key = dpp_max_step<0x111, 0xf, 0xf>(key);  // row_shr:1
    key = dpp_max_step<0x112, 0xf, 0xf>(key);  // row_shr:2
    key = dpp_max_step<0x114, 0xf, 0xe>(key);  // row_shr:4
    key = dpp_max_step<0x118, 0xf, 0xc>(key);  // row_shr:8
    key = dpp_max_step<0x142, 0xa, 0xf>(key);  // row_bcast:15
    key = dpp_max_step<0x143, 0xc, 0xf>(key);  // row_bcast:31
    return key;
}

// 12 instructions per point; #k expands to an inline constant (0..31).
#define PT(k)                                                     \
    "v_sub_f32 %[t0], %[px" #k "], %[cx]\n\t"                     \
    "v_sub_f32 %[t1], %[py" #k "], %[cy]\n\t"                     \
    "v_sub_f32 %[t2], %[pz" #k "], %[cz]\n\t"                     \
    "v_mul_f32 %[t0], %[t0], %[t0]\n\t"                           \
    "v_mul_f32 %[t1], %[t1], %[t1]\n\t"                           \
    "v_mul_f32 %[t2], %[t2], %[t2]\n\t"                           \
    "v_add_f32 %[t0], %[t0], %[t1]\n\t"                           \
    "v_add_f32 %[t0], %[t0], %[t2]\n\t"                           \
    "v_min_f32 %[d" #k "], %[d" #k "], %[t0]\n\t"                 \
    "v_cmp_le_f32 vcc, %[d" #k "], %[bv]\n\t"                     \
    "v_cndmask_b32 %[bv], %[d" #k "], %[bv], vcc\n\t"             \
    "v_cndmask_b32 %[bi], " #k ", %[bi], vcc\n\t"

__global__ __launch_bounds__(BLOCK)
__attribute__((amdgpu_waves_per_eu(2, 2))) void fps_kernel(
    const float* __restrict__ xyz,   // [B,3,N]
    int* __restrict__ cent)          // [B,NPOINT] workspace
{
    const int b   = blockIdx.x;
    const int tid = threadIdx.x;
    const float* X = xyz + (size_t)b * 3 * N_PTS;
    const float* Y = X + N_PTS;
    const float* Z = X + 2 * N_PTS;

    float px[KPT], py[KPT], pz[KPT], dst[KPT];
#pragma unroll
    for (int k = 0; k < KPT; ++k) {
        const int p = tid + k * BLOCK;   // strided: coalesced, ascending/thread
        px[k] = X[p];
        py[k] = Y[p];
        pz[k] = Z[p];
        dst[k] = 1e10f;                  // BIG
    }

    __shared__ unsigned long long s_key[2][NWAVE];  // double-buffered

    const int wave = tid >> 6;
    const int lane = tid & 63;

    // ---- initial far: argmax over x (first occurrence: ascending, strict >)
    int far;
    {
        float bv = px[0];
        int   bi = tid;
#pragma unroll
        for (int k = 1; k < KPT; ++k) {
            if (px[k] > bv) { bv = px[k]; bi = tid + k * BLOCK; }
        }
        const unsigned long long key = wave_max_key(pack_key(bv, bi));
        if (lane == 63) s_key[0][wave] = key;
        __syncthreads();
        const unsigned long long* sk = s_key[0];
        const unsigned long long bkk =
            umax64(umax64(umax64(sk[0], sk[1]), umax64(sk[2], sk[3])),
                   umax64(umax64(sk[4], sk[5]), umax64(sk[6], sk[7])));
        far = __builtin_amdgcn_readfirstlane(key_idx(bkk)) &
              (N_PTS - 1);               // fault guard: always in-bounds
    }

    // ---- main FPS loop: one barrier per iteration ----
    for (int it = 0; it < NPOINT; ++it) {
        if (tid == 0) cent[b * NPOINT + it] = far;   // record PRE-update far
        if (it == NPOINT - 1) break;                 // last update is unused

        // centroid coords: far is uniform (SGPR) -> scalar broadcast loads;
        // bound as "v" below (one v_mov each, negligible).
        const float cx = X[far];
        const float cy = Y[far];
        const float cz = Z[far];

        float nbv = -1.0f;
        int   nbi = 0;                               // local k in [0,32)
        float t0, t1, t2;
        asm volatile(
            PT(0)  PT(1)  PT(2)  PT(3)  PT(4)  PT(5)  PT(6)  PT(7)
            PT(8)  PT(9)  PT(10) PT(11) PT(12) PT(13) PT(14) PT(15)
            PT(16) PT(17) PT(18) PT(19) PT(20) PT(21) PT(22) PT(23)
            PT(24) PT(25) PT(26) PT(27) PT(28) PT(29) PT(30) PT(31)
            : [d0] "+v"(dst[0]),  [d1] "+v"(dst[1]),  [d2] "+v"(dst[2]),
              [d3] "+v"(dst[3]),  [d4] "+v"(dst[4]),  [d5] "+v"(dst[5]),
              [d6] "+v"(dst[6]),  [d7] "+v"(dst[7]),  [d8] "+v"(dst[8]),
              [d9] "+v"(dst[9]),  [d10] "+v"(dst[10]), [d11] "+v"(dst[11]),
              [d12] "+v"(dst[12]), [d13] "+v"(dst[13]), [d14] "+v"(dst[14]),
              [d15] "+v"(dst[15]), [d16] "+v"(dst[16]), [d17] "+v"(dst[17]),
              [d18] "+v"(dst[18]), [d19] "+v"(dst[19]), [d20] "+v"(dst[20]),
              [d21] "+v"(dst[21]), [d22] "+v"(dst[22]), [d23] "+v"(dst[23]),
              [d24] "+v"(dst[24]), [d25] "+v"(dst[25]), [d26] "+v"(dst[26]),
              [d27] "+v"(dst[27]), [d28] "+v"(dst[28]), [d29] "+v"(dst[29]),
              [d30] "+v"(dst[30]), [d31] "+v"(dst[31]),
              [bv] "+v"(nbv), [bi] "+v"(nbi),
              [t0] "=&v"(t0), [t1] "=&v"(t1), [t2] "=&v"(t2)
            : [px0] "v"(px[0]),  [px1] "v"(px[1]),  [px2] "v"(px[2]),
              [px3] "v"(px[3]),  [px4] "v"(px[4]),  [px5] "v"(px[5]),
              [px6] "v"(px[6]),  [px7] "v"(px[7]),  [px8] "v"(px[8]),
              [px9] "v"(px[9]),  [px10] "v"(px[10]), [px11] "v"(px[11]),
              [px12] "v"(px[12]), [px13] "v"(px[13]), [px14] "v"(px[14]),
              [px15] "v"(px[15]), [px16] "v"(px[16]), [px17] "v"(px[17]),
              [px18] "v"(px[18]), [px19] "v"(px[19]), [px20] "v"(px[20]),
              [px21] "v"(px[21]), [px22] "v"(px[22]), [px23] "v"(px[23]),
              [px24] "v"(px[24]), [px25] "v"(px[25]), [px26] "v"(px[26]),
              [px27] "v"(px[27]), [px28] "v"(px[28]), [px29] "v"(px[29]),
              [px30] "v"(px[30]), [px31] "v"(px[31]),
              [py0] "v"(py[0]),  [py1] "v"(py[1]),  [py2] "v"(py[2]),
              [py3] "v"(py[3]),  [py4] "v"(py[4]),  [py5] "v"(py[5]),
              [py6] "v"(py[6]),  [py7] "v"(py[7]),  [py8] "v"(py[8]),
              [py9] "v"(py[9]),  [py10] "v"(py[10]), [py11] "v"(py[11]),
              [py12] "v"(py[12]), [py13] "v"(py[13]), [py14] "v"(py[14]),
              [py15] "v"(py[15]), [py16] "v"(py[16]), [py17] "v"(py[17]),
              [py18] "v"(py[18]), [py19] "v"(py[19]), [py20] "v"(py[20]),
              [py21] "v"(py[21]), [py22] "v"(py[22]), [py23] "v"(py[23]),
              [py24] "v"(py[24]), [py25] "v"(py[25]), [py26] "v"(py[26]),
              [py27] "v"(py[27]), [py28] "v"(py[28]), [py29] "v"(py[29]),
              [py30] "v"(py[30]), [py31] "v"(py[31]),
              [pz0] "v"(pz[0]),  [pz1] "v"(pz[1]),  [pz2] "v"(pz[2]),
              [pz3] "v"(pz[3]),  [pz4] "v"(pz[4]),  [pz5] "v"(pz[5]),
              [pz6] "v"(pz[6]),  [pz7] "v"(pz[7]),  [pz8] "v"(pz[8]),
              [pz9] "v"(pz[9]),  [pz10] "v"(pz[10]), [pz11] "v"(pz[11]),
              [pz12] "v"(pz[12]), [pz13] "v"(pz[13]), [pz14] "v"(pz[14]),
              [pz15] "v"(pz[15]), [pz16] "v"(pz[16]), [pz17] "v"(pz[17]),
              [pz18] "v"(pz[18]), [pz19] "v"(pz[19]), [pz20] "v"(pz[20]),
              [pz21] "v"(pz[21]), [pz22] "v"(pz[22]), [pz23] "v"(pz[23]),
              [pz24] "v"(pz[24]), [pz25] "v"(pz[25]), [pz26] "v"(pz[26]),
              [pz27] "v"(pz[27]), [pz28] "v"(pz[28]), [pz29] "v"(pz[29]),
              [pz30] "v"(pz[30]), [pz31] "v"(pz[31]),
              [cx] "v"(cx), [cy] "v"(cy), [cz] "v"(cz)
            : "vcc");

        const unsigned long long key =
            wave_max_key(pack_key(nbv, tid + (nbi << 9)));
        const int buf = (it + 1) & 1;
        if (lane == 63) s_key[buf][wave] = key;
        __syncthreads();

        const unsigned long long* sk = s_key[buf];
        const unsigned long long bkk =
            umax64(umax64(umax64(sk[0], sk[1]), umax64(sk[2], sk[3])),
                   umax64(umax64(sk[4], sk[5]), umax64(sk[6], sk[7])));
        far = __builtin_amdgcn_readfirstlane(key_idx(bkk)) &
              (N_PTS - 1);               // fault guard
    }
}

// ---------------------------------------------------------------------------
// Ball query, nsample=1: one wave per centroid; scan 64-point chunks from
// index 0, first hit wins (== min index within radius). Distance replicated
// as the reference einsum: ((-2*dot) + |c|^2) + |p|^2; keep-test d <= 0.25.
// ---------------------------------------------------------------------------
__global__ __launch_bounds__(256) void ballq_kernel(
    const float* __restrict__ xyz,   // [B,3,N]
    const int* __restrict__ cent,    // [B,NPOINT]
    int* __restrict__ out)           // [B,NPOINT]
{
    const int gw   = (blockIdx.x * 256 + threadIdx.x) >> 6; // global wave id
    const int lane = threadIdx.x & 63;
    const int b = gw / NPOINT;
    const int s = gw % NPOINT;

    const float* X = xyz + (size_t)b * 3 * N_PTS;
    const float* Y = X + N_PTS;
    const float* Z = X + 2 * N_PTS;

    const int ci = cent[b * NPOINT + s] & (N_PTS - 1);  // fault guard
    const float cx = X[ci];
    const float cy = Y[ci];
    const float cz = Z[ci];
    const float cn = __fadd_rn(
        __fadd_rn(__fmul_rn(cx, cx), __fmul_rn(cy, cy)), __fmul_rn(cz, cz));

    int res = N_PTS;
    for (int base = 0; base < N_PTS; base += 64) {
        const int p = base + lane;
        const float x = X[p];
        const float y = Y[p];
        const float z = Z[p];
        const float dot = __fadd_rn(
            __fadd_rn(__fmul_rn(x, cx), __fmul_rn(y, cy)), __fmul_rn(z, cz));
        const float pn = __fadd_rn(
            __fadd_rn(__fmul_rn(x, x), __fmul_rn(y, y)), __fmul_rn(z, z));
        const float d = __fadd_rn(__fadd_rn(__fmul_rn(-2.0f, dot), cn), pn);
        const bool hit = !(d > 0.25f);
        const unsigned long long m = __ballot(hit);
        if (m) {                       // wave-uniform branch
            res = base + (__ffsll((long long)m) - 1);
            break;
        }
    }
    if (lane == 0) out[b * NPOINT + s] = res;
}

extern "C" void kernel_launch(void* const* d_in, const int* in_sizes, int n_in,
                              void* d_out, int out_size, void* d_ws, size_t ws_size,
                              hipStream_t stream) {
    const float* xyz = (const float*)d_in[0];
    const int B = in_sizes[1] / 16;          // cls_label is [B,16]
    int* cent = (int*)d_ws;                  // [B, NPOINT] scratch
    int* out  = (int*)d_out;                 // int32 [B, NPOINT, 1]

    fps_kernel<<<B, BLOCK, 0, stream>>>(xyz, cent);

    const int nwaves  = B * NPOINT;          // one wave per centroid
    const int nblocks = nwaves / 4;          // 256 threads = 4 waves/block
    ballq_kernel<<<nblocks, 256, 0, stream>>>(xyz, cent, out);
}

// Round 12
// 1785.214 us; speedup vs baseline: 1.1478x; 1.0515x over previous
//
#include <hip/hip_runtime.h>

// Problem shape (fixed by setup_inputs): B=4, N=16384, NPOINT=1024, nsample=1,
// radius=0.5. xyz input layout is [B,3,N]. Output: int32 [B,NPOINT,1].
//
// FPS: one block per batch (R10 measured cross-block sync at ~1.9 us/iter —
// structurally dead). 512 threads = 8 waves = 2 waves/SIMD, 32 points/thread
// held as 16 f32x2 pairs.
//
// Round-12 change vs R6 (single variable): the scan's distance core uses
// v_pk_add_f32 / v_pk_mul_f32 (HW-verified helpers from R3) — 8 pk ops per
// point-PAIR replace 16 scalar ops — and the argmax tracking uses DUAL
// accumulators (even/odd slots) so the cndmask dependency chain is two
// independent 16-chains instead of one 32-chain (R11 showed dependency
// stalls in the scan matter at 2 waves/SIMD). Merge preserves numpy
// first-occurrence exactly: both accumulators share tid, so on value tie the
// smaller slot wins (k1 odd vs k0 even, never equal).
// R11 also falsified the AGPR/remat theory (hard "v" pins changed nothing),
// so this round goes back to letting the compiler schedule C++-level ops.
//
// Per iteration (ONE barrier, R6-verified tail):
//   pk distance update (per half: ((dx*dx+dy*dy)+dz*dz), each op RN, no FMA;
//   pk_add with exact-negated centroid == RN sub) -> fminf per half ->
//   strict-'>' per-half argmax with inline-const slot ids -> merge ->
//   packed (value<<32 | 16383-idx) key -> 6-step DPP wave max -> lane 63
//   writes LDS (double-buffered) -> barrier -> 8-key tree -> readfirstlane.

constexpr int N_PTS  = 16384;
constexpr int NPOINT = 1024;
constexpr int BLOCK  = 512;            // 8 waves -> 2 waves/SIMD
constexpr int KPT    = N_PTS / BLOCK;  // 32 points/thread
constexpr int KP2    = KPT / 2;        // 16 register pairs
constexpr int NWAVE  = BLOCK / 64;     // 8

typedef float f32x2 __attribute__((ext_vector_type(2)));

// HW-verified in R3 (compiled, ran, absmax 0): per-half RN add/mul.
__device__ inline f32x2 pk_add(f32x2 a, f32x2 b) {
    f32x2 d;
    asm("v_pk_add_f32 %0, %1, %2" : "=v"(d) : "v"(a), "v"(b));
    return d;
}
__device__ inline f32x2 pk_mul(f32x2 a, f32x2 b) {
    f32x2 d;
    asm("v_pk_mul_f32 %0, %1, %2" : "=v"(d) : "v"(a), "v"(b));
    return d;
}

__device__ inline unsigned long long pack_key(float v, int idx) {
    return ((unsigned long long)__float_as_uint(v) << 32) |
           (unsigned)(N_PTS - 1 - idx);
}
__device__ inline int key_idx(unsigned long long k) {
    return N_PTS - 1 - (int)(k & 0xFFFFu);
}
__device__ inline unsigned long long umax64(unsigned long long a,
                                            unsigned long long b) {
    return a > b ? a : b;
}

template <int CTRL, int RM, int BM>
__device__ inline unsigned long long dpp_max_step(unsigned long long key) {
    const int lo = (int)(unsigned)key;
    const int hi = (int)(unsigned)(key >> 32);
    const unsigned mlo =
        (unsigned)__builtin_amdgcn_update_dpp(lo, lo, CTRL, RM, BM, false);
    const unsigned mhi =
        (unsigned)__builtin_amdgcn_update_dpp(hi, hi, CTRL, RM, BM, false);
    const unsigned long long moved = ((unsigned long long)mhi << 32) | mlo;
    return key > moved ? key : moved;
}
// Full 64-lane max; result valid in lane 63 (HW-verified rounds 5-9).
__device__ inline unsigned long long wave_max_key(unsigned long long key) {
    key = dpp_max_step<0x111, 0xf, 0xf>(key);  // row_shr:1
    key = dpp_max_step<0x112, 0xf, 0xf>(key);  // row_shr:2
    key = dpp_max_step<0x114, 0xf, 0xe>(key);  // row_shr:4
    key = dpp_max_step<0x118, 0xf, 0xc>(key);  // row_shr:8
    key = dpp_max_step<0x142, 0xa, 0xf>(key);  // row_bcast:15
    key = dpp_max_step<0x143, 0xc, 0xf>(key);  // row_bcast:31
    return key;
}

__global__ __launch_bounds__(BLOCK)
__attribute__((amdgpu_waves_per_eu(2, 2))) void fps_kernel(
    const float* __restrict__ xyz,   // [B,3,N]
    int* __restrict__ cent)          // [B,NPOINT] workspace
{
    const int b   = blockIdx.x;
    const int tid = threadIdx.x;
    const float* X = xyz + (size_t)b * 3 * N_PTS;
    const float* Y = X + N_PTS;
    const float* Z = X + 2 * N_PTS;

    f32x2 px[KP2], py[KP2], pz[KP2], dd[KP2];
#pragma unroll
    for (int k = 0; k < KP2; ++k) {
        const int p0 = tid + (2 * k) * BLOCK;      // coalesced per component
        const int p1 = tid + (2 * k + 1) * BLOCK;
        px[k] = f32x2{X[p0], X[p1]};
        py[k] = f32x2{Y[p0], Y[p1]};
        pz[k] = f32x2{Z[p0], Z[p1]};
        dd[k] = f32x2{1e10f, 1e10f};               // BIG
    }
    // Keep the point cloud resident (volatile: non-clonable/remat-able).
#pragma unroll
    for (int k = 0; k < KP2; ++k)
        asm volatile("" : "+v"(px[k]), "+v"(py[k]), "+v"(pz[k]));

    __shared__ unsigned long long s_key[2][NWAVE];  // double-buffered

    const int wave = tid >> 6;
    const int lane = tid & 63;

    // ---- initial far: argmax over x (first occurrence: ascending, strict >)
    int far;
    {
        float bv = px[0].x;
        int   bk = 0;
#pragma unroll
        for (int k = 0; k < KP2; ++k) {
            if (px[k].x > bv) { bv = px[k].x; bk = 2 * k; }
            if (px[k].y > bv) { bv = px[k].y; bk = 2 * k + 1; }
        }
        const unsigned long long key =
            wave_max_key(pack_key(bv, tid + bk * BLOCK));
        if (lane == 63) s_key[0][wave] = key;
        __syncthreads();
        const unsigned long long* sk = s_key[0];
        const unsigned long long bkk =
            umax64(umax64(umax64(sk[0], sk[1]), umax64(sk[2], sk[3])),
                   umax64(umax64(sk[4], sk[5]), umax64(sk[6], sk[7])));
        far = __builtin_amdgcn_readfirstlane(key_idx(bkk)) &
              (N_PTS - 1);               // fault guard: always in-bounds
    }

    // ---- main FPS loop: one barrier per iteration ----
    for (int it = 0; it < NPOINT; ++it) {
        if (tid == 0) cent[b * NPOINT + it] = far;   // record PRE-update far
        if (it == NPOINT - 1) break;                 // last update is unused

        // centroid coords: far is uniform (SGPR) -> scalar broadcast loads
        const float cx = X[far];
        const float cy = Y[far];
        const float cz = Z[far];
        const f32x2 ncx = {-cx, -cx};                // exact negation
        const f32x2 ncy = {-cy, -cy};
        const f32x2 ncz = {-cz, -cz};

        // Dual-accumulator scan: even slots -> (bv0,k0), odd -> (bv1,k1).
        float bv0 = -1.0f, bv1 = -1.0f;
        int   k0  = 0,     k1  = 1;                  // slot ids in [0,32)
#pragma unroll
        for (int k = 0; k < KP2; ++k) {
            const f32x2 dx = pk_add(px[k], ncx);     // == p - c, RN per half
            const f32x2 dy = pk_add(py[k], ncy);
            const f32x2 dz = pk_add(pz[k], ncz);
            const f32x2 d  = pk_add(pk_add(pk_mul(dx, dx), pk_mul(dy, dy)),
                                    pk_mul(dz, dz));
            const float n0 = fminf(dd[k].x, d.x);
            const float n1 = fminf(dd[k].y, d.y);
            dd[k].x = n0;
            dd[k].y = n1;
            if (n0 > bv0) { bv0 = n0; k0 = 2 * k; }      // inline-const slot
            if (n1 > bv1) { bv1 = n1; k1 = 2 * k + 1; }
        }
        // Merge with exact first-occurrence: same tid, so tie -> smaller slot.
        float nbv;
        int   nbk;
        if (bv1 > bv0 || (bv1 == bv0 && k1 < k0)) { nbv = bv1; nbk = k1; }
        else                                      { nbv = bv0; nbk = k0; }

        const unsigned long long key =
            wave_max_key(pack_key(nbv, tid + (nbk << 9)));
        const int buf = (it + 1) & 1;
        if (lane == 63) s_key[buf][wave] = key;
        __syncthreads();

        const unsigned long long* sk = s_key[buf];
        const unsigned long long bkk =
            umax64(umax64(umax64(sk[0], sk[1]), umax64(sk[2], sk[3])),
                   umax64(umax64(sk[4], sk[5]), umax64(sk[6], sk[7])));
        far = __builtin_amdgcn_readfirstlane(key_idx(bkk)) &
              (N_PTS - 1);               // fault guard
    }
}

// ---------------------------------------------------------------------------
// Ball query, nsample=1: one wave per centroid; scan 64-point chunks from
// index 0, first hit wins (== min index within radius). Distance replicated
// as the reference einsum: ((-2*dot) + |c|^2) + |p|^2; keep-test d <= 0.25.
// ---------------------------------------------------------------------------
__global__ __launch_bounds__(256) void ballq_kernel(
    const float* __restrict__ xyz,   // [B,3,N]
    const int* __restrict__ cent,    // [B,NPOINT]
    int* __restrict__ out)           // [B,NPOINT]
{
    const int gw   = (blockIdx.x * 256 + threadIdx.x) >> 6; // global wave id
    const int lane = threadIdx.x & 63;
    const int b = gw / NPOINT;
    const int s = gw % NPOINT;

    const float* X = xyz + (size_t)b * 3 * N_PTS;
    const float* Y = X + N_PTS;
    const float* Z = X + 2 * N_PTS;

    const int ci = cent[b * NPOINT + s] & (N_PTS - 1);  // fault guard
    const float cx = X[ci];
    const float cy = Y[ci];
    const float cz = Z[ci];
    const float cn = __fadd_rn(
        __fadd_rn(__fmul_rn(cx, cx), __fmul_rn(cy, cy)), __fmul_rn(cz, cz));

    int res = N_PTS;
    for (int base = 0; base < N_PTS; base += 64) {
        const int p = base + lane;
        const float x = X[p];
        const float y = Y[p];
        const float z = Z[p];
        const float dot = __fadd_rn(
            __fadd_rn(__fmul_rn(x, cx), __fmul_rn(y, cy)), __fmul_rn(z, cz));
        const float pn = __fadd_rn(
            __fadd_rn(__fmul_rn(x, x), __fmul_rn(y, y)), __fmul_rn(z, z));
        const float d = __fadd_rn(__fadd_rn(__fmul_rn(-2.0f, dot), cn), pn);
        const bool hit = !(d > 0.25f);
        const unsigned long long m = __ballot(hit);
        if (m) {                       // wave-uniform branch
            res = base + (__ffsll((long long)m) - 1);
            break;
        }
    }
    if (lane == 0) out[b * NPOINT + s] = res;
}

extern "C" void kernel_launch(void* const* d_in, const int* in_sizes, int n_in,
                              void* d_out, int out_size, void* d_ws, size_t ws_size,
                              hipStream_t stream) {
    const float* xyz = (const float*)d_in[0];
    const int B = in_sizes[1] / 16;          // cls_label is [B,16]
    int* cent = (int*)d_ws;                  // [B, NPOINT] scratch
    int* out  = (int*)d_out;                 // int32 [B, NPOINT, 1]

    fps_kernel<<<B, BLOCK, 0, stream>>>(xyz, cent);

    const int nwaves  = B * NPOINT;          // one wave per centroid
    const int nblocks = nwaves / 4;          // 256 threads = 4 waves/block
    ballq_kernel<<<nblocks, 256, 0, stream>>>(xyz, cent, out);
}